// Round 4
// baseline (47705.270 us; speedup 1.0000x reference)
//
#include <hip/hip_runtime.h>
#include <math.h>

#define T_LEN 512
#define NB    32
#define EMB_  41
#define IN0_  42
#define HID_  800
#define G4_   3200
#define IN1_  1600
#define NU    20
#define NCH   100   // blocks per direction

typedef unsigned short u16;
typedef unsigned int   u32;
typedef __attribute__((ext_vector_type(8))) short short8;
typedef __attribute__((ext_vector_type(4))) float f32x4;

__device__ __forceinline__ float bf2f(u16 v) {
    union { u32 u; float f; } c; c.u = ((u32)v) << 16; return c.f;
}
__device__ __forceinline__ u16 f2bf(float f) {
    union { float f; u32 u; } c; c.f = f;
    u32 r = (c.u + 0x7fffu + ((c.u >> 16) & 1u)) >> 16;
    return (u16)r;
}
__device__ __forceinline__ short cvt_hl(float v, int hl) {
    u16 hi = f2bf(v);
    return hl ? (short)f2bf(v - bf2f(hi)) : (short)hi;
}
__device__ __forceinline__ f32x4 mfma16(short8 a, short8 b, f32x4 c) {
    return __builtin_amdgcn_mfma_f32_16x16x32_bf16(a, b, c, 0, 0, 0);
}

// per-direction barrier among NCH co-resident blocks (device-scope release/acquire)
__device__ __forceinline__ void dir_barrier(int* bar, int s, int tid) {
    __threadfence();                 // release this block's global writes
    __syncthreads();
    if (tid == 0) {
        atomicAdd(&bar[s], 1);       // device-scope RMW [m20]
        while (__hip_atomic_load(&bar[s], __ATOMIC_RELAXED, __HIP_MEMORY_SCOPE_AGENT) < NCH)
            __builtin_amdgcn_s_sleep(2);
    }
    __syncthreads();
    __threadfence();                 // acquire: invalidate stale L1/L2 before reading peers' data
}

// ---------------- Layer 0: persistent, 200 blocks x 256 threads ----------------
// Block (d,ch): 8 hidden units, both gate-pairs; 4 waves = (pair p, hilo hl).
// whh0 hi/lo A-frags in VGPRs (25 x short8). Exact fp32 input dot from LDS.
__global__ __launch_bounds__(256, 1)
void lstm0_persist(const float* __restrict__ seq, const float* __restrict__ wih0,
                   const float* __restrict__ whh0, const float* __restrict__ bias,
                   u16* __restrict__ h0f, u16* __restrict__ hB, float* __restrict__ c_st,
                   int* __restrict__ bar)
{
    __shared__ __align__(16) float part[2*2*2*16*16];   // 8 KB
    __shared__ __align__(16) float w0l[32*48];          // [ju*4+g][48] w_ih0 rows (k<41)
    __shared__ __align__(16) float xsl[32*48];          // [b][48] seq[t] staging
    const int tid = threadIdx.x;
    const int d = blockIdx.x / NCH, ch = blockIdx.x % NCH;
    const int w = tid >> 6, l = tid & 63;
    const int p = w & 1, hl = w >> 1;
    int* mybar = bar + d*T_LEN;

    // setup: whh0 -> hi/lo bf16 A-frags in registers
    short8 wreg[25];
    {
        const int m = l & 15, g = p*2 + (m>>3), j = ch*8 + (m&7);
        const float* base = whh0 + ((size_t)(d*G4_ + g*HID_ + j))*HID_ + (l>>4)*8;
#pragma unroll
        for (int kc = 0; kc < 25; ++kc) {
            float4 f0 = *(const float4*)(base + kc*32);
            float4 f1 = *(const float4*)(base + kc*32 + 4);
            short8 v;
            v[0]=cvt_hl(f0.x,hl); v[1]=cvt_hl(f0.y,hl); v[2]=cvt_hl(f0.z,hl); v[3]=cvt_hl(f0.w,hl);
            v[4]=cvt_hl(f1.x,hl); v[5]=cvt_hl(f1.y,hl); v[6]=cvt_hl(f1.z,hl); v[7]=cvt_hl(f1.w,hl);
            wreg[kc] = v;
        }
    }
    // setup: w_ih0 rows -> LDS (static across steps)
    for (int idx = tid; idx < 32*EMB_; idx += 256) {
        int r = idx / EMB_, k = idx % EMB_;     // r = ju*4+g
        int ju_ = r >> 2, g = r & 3;
        w0l[r*48 + k] = wih0[((size_t)(d*G4_ + g*HID_ + ch*8 + ju_))*IN0_ + k];
    }
    // update-thread constants
    const int ju = tid >> 5, b = tid & 31;
    const int j = ch*8 + ju;
    const int nt = b >> 4, n = b & 15;
    float biasr[4], wpos[4];
#pragma unroll
    for (int g = 0; g < 4; ++g) {
        biasr[g] = bias[d*G4_ + g*HID_ + j];
        wpos[g]  = wih0[((size_t)(d*G4_ + g*HID_ + j))*IN0_ + EMB_];   // exact position feature
    }
    float* cp = c_st + (size_t)(d*NB + b)*HID_ + j;
    const int kcj = j >> 5, wij = j & 31;
    const int llj = ((wij>>3)<<4) | n, iij = wij & 7;
    const int k0 = d*HID_ + j, kc0 = k0 >> 5, wi0 = k0 & 31;
    const int ll0 = ((wi0>>3)<<4) | n, ii0 = wi0 & 7;
    __syncthreads();

    for (int s = 0; s < T_LEN; ++s) {
        const int t = d ? (T_LEN-1-s) : s;
        const u16* hcur = hB + (size_t)((s&1)*2 + d)*25600;
        u16*       hnxt = hB + (size_t)(((s&1)^1)*2 + d)*25600;

        f32x4 acc0 = {0.f,0.f,0.f,0.f}, acc1 = {0.f,0.f,0.f,0.f};
#pragma unroll
        for (int kc = 0; kc < 25; ++kc) {
            short8 b0 = *(const short8*)(hcur + kc*1024 + l*8);
            short8 b1 = *(const short8*)(hcur + kc*1024 + 512 + l*8);
            acc0 = mfma16(wreg[kc], b0, acc0);
            acc1 = mfma16(wreg[kc], b1, acc1);
        }
        {
            const int mrow = (l>>4)*4, nn = l & 15;
#pragma unroll
            for (int r = 0; r < 4; ++r) {
                part[(((p*2+hl)*2 + 0)*16 + mrow + r)*16 + nn] = acc0[r];
                part[(((p*2+hl)*2 + 1)*16 + mrow + r)*16 + nn] = acc1[r];
            }
        }
        for (int idx = tid; idx < 32*EMB_; idx += 256)
            xsl[(idx/EMB_)*48 + idx%EMB_] = seq[(size_t)t*(NB*EMB_) + idx];
        __syncthreads();

        float dot0 = 0.f, dot1 = 0.f, dot2 = 0.f, dot3 = 0.f;
        {
            const float* wr = &w0l[ju*4*48];
            const float* xr = &xsl[b*48];
#pragma unroll
            for (int k4 = 0; k4 < 40; k4 += 4) {
                float4 xk = *(const float4*)(xr + k4);
                float4 w0 = *(const float4*)(wr + 0*48 + k4);
                float4 w1 = *(const float4*)(wr + 1*48 + k4);
                float4 w2 = *(const float4*)(wr + 2*48 + k4);
                float4 w3 = *(const float4*)(wr + 3*48 + k4);
                dot0 += w0.x*xk.x + w0.y*xk.y + w0.z*xk.z + w0.w*xk.w;
                dot1 += w1.x*xk.x + w1.y*xk.y + w1.z*xk.z + w1.w*xk.w;
                dot2 += w2.x*xk.x + w2.y*xk.y + w2.z*xk.z + w2.w*xk.w;
                dot3 += w3.x*xk.x + w3.y*xk.y + w3.z*xk.z + w3.w*xk.w;
            }
            float xk = xr[40];
            dot0 += wr[0*48+40]*xk; dot1 += wr[1*48+40]*xk;
            dot2 += wr[2*48+40]*xk; dot3 += wr[3*48+40]*xk;
        }
        float v[4] = {dot0, dot1, dot2, dot3};
#pragma unroll
        for (int g = 0; g < 4; ++g) {
            const int pp = g >> 1, m = (g & 1)*8 + ju;
            v[g] += part[(((pp*2+0)*2 + nt)*16 + m)*16 + n]
                  + part[(((pp*2+1)*2 + nt)*16 + m)*16 + n]
                  + biasr[g] + (float)t * wpos[g];
        }
        float ig = 1.f/(1.f + expf(-v[0]));
        float fg = 1.f/(1.f + expf(-v[1]));
        float gg = tanhf(v[2]);
        float og = 1.f/(1.f + expf(-v[3]));
        float cn = fg * (*cp) + ig * gg;
        *cp = cn;
        u16 hb = f2bf(og * tanhf(cn));
        hnxt[(kcj*2 + nt)*512 + llj*8 + iij] = hb;
        h0f[(size_t)t*51200 + (kc0*2 + nt)*512 + ll0*8 + ii0] = hb;

        dir_barrier(mybar, s, tid);
    }
}

// reduce previous step's logit partials: block ch owns k = ch + 100*m slices
__device__ __forceinline__ void reduce_stage(const float* __restrict__ stage, float* __restrict__ logits2,
                                             int d, int ch, int sbuf, int tp, int tid)
{
    const int ki = tid >> 5, l32 = tid & 31;
    if (ki >= 7) return;
    const int k = ch + ki*NCH;
    if (k >= 640) return;
    const float* sb = stage + (size_t)(d*2 + sbuf)*NCH*640;
    float sum = 0.f;
    for (int cq = l32; cq < NCH; cq += 32) sum += sb[(size_t)cq*640 + k];
#pragma unroll
    for (int off = 16; off; off >>= 1) sum += __shfl_down(sum, off, 32);
    if (l32 == 0) logits2[((size_t)d*T_LEN + tp)*640 + k] = sum;
}

// ---------------- Layer 1: persistent; fused x-GEMM + final linear ----------------
__global__ __launch_bounds__(256, 1)
void lstm1_persist(const float* __restrict__ wih1, const float* __restrict__ whh1,
                   const float* __restrict__ bias, const float* __restrict__ lin_w,
                   const u16* __restrict__ h0f, u16* __restrict__ hB, float* __restrict__ c_st,
                   int* __restrict__ bar, float* __restrict__ stage, float* __restrict__ logits2)
{
    __shared__ __align__(16) float part[2*2*2*16*16];   // 8 KB
    __shared__ __align__(16) u16  wihL[2*50*512];       // 100 KB w_ih1 A-frags
    __shared__ float lwc[8*NU];
    __shared__ float hblk[8*NB];
    const int tid = threadIdx.x;
    const int d = blockIdx.x / NCH, ch = blockIdx.x % NCH;
    const int w = tid >> 6, l = tid & 63;
    const int p = w & 1, hl = w >> 1;
    int* mybar = bar + d*T_LEN;

    short8 wreg[25];
    {
        const int m = l & 15, g = p*2 + (m>>3), j = ch*8 + (m&7);
        const float* base = whh1 + ((size_t)(d*G4_ + g*HID_ + j))*HID_ + (l>>4)*8;
#pragma unroll
        for (int kc = 0; kc < 25; ++kc) {
            float4 f0 = *(const float4*)(base + kc*32);
            float4 f1 = *(const float4*)(base + kc*32 + 4);
            short8 v;
            v[0]=cvt_hl(f0.x,hl); v[1]=cvt_hl(f0.y,hl); v[2]=cvt_hl(f0.z,hl); v[3]=cvt_hl(f0.w,hl);
            v[4]=cvt_hl(f1.x,hl); v[5]=cvt_hl(f1.y,hl); v[6]=cvt_hl(f1.z,hl); v[7]=cvt_hl(f1.w,hl);
            wreg[kc] = v;
        }
    }
    // w_ih1 A-frags -> LDS (once): octet o = ((p*50+kc)*64+l)
    for (int o = tid; o < 6400; o += 256) {
        int pp = o / 3200, r = o % 3200, kc = r >> 6, ll = r & 63;
        int m = ll & 15, g = pp*2 + (m>>3), jj = ch*8 + (m&7);
        const float* base = wih1 + ((size_t)(d*G4_ + g*HID_ + jj))*IN1_ + kc*32 + (ll>>4)*8;
        float4 f0 = *(const float4*)base;
        float4 f1 = *(const float4*)(base + 4);
        short8 v;
        v[0]=(short)f2bf(f0.x); v[1]=(short)f2bf(f0.y); v[2]=(short)f2bf(f0.z); v[3]=(short)f2bf(f0.w);
        v[4]=(short)f2bf(f1.x); v[5]=(short)f2bf(f1.y); v[6]=(short)f2bf(f1.z); v[7]=(short)f2bf(f1.w);
        *(short8*)&wihL[o*8] = v;
    }
    if (tid < 8*NU) {
        int jju = tid / NU, u = tid % NU;
        lwc[tid] = lin_w[(size_t)u*IN1_ + d*HID_ + ch*8 + jju];
    }
    const int ju = tid >> 5, b = tid & 31;
    const int j = ch*8 + ju;
    const int nt = b >> 4, n = b & 15;
    float biasr[4];
#pragma unroll
    for (int g = 0; g < 4; ++g) biasr[g] = bias[d*G4_ + g*HID_ + j];
    float* cp = c_st + (size_t)(d*NB + b)*HID_ + j;
    const int kcj = j >> 5, wij = j & 31;
    const int llj = ((wij>>3)<<4) | n, iij = wij & 7;
    __syncthreads();

    for (int s = 0; s < T_LEN; ++s) {
        const int t = d ? (T_LEN-1-s) : s;
        const u16* hcur = hB + (size_t)((s&1)*2 + d)*25600;
        u16*       hnxt = hB + (size_t)(((s&1)^1)*2 + d)*25600;

        f32x4 acc0 = {0.f,0.f,0.f,0.f}, acc1 = {0.f,0.f,0.f,0.f};
#pragma unroll
        for (int kc = 0; kc < 25; ++kc) {
            short8 b0 = *(const short8*)(hcur + kc*1024 + l*8);
            short8 b1 = *(const short8*)(hcur + kc*1024 + 512 + l*8);
            acc0 = mfma16(wreg[kc], b0, acc0);
            acc1 = mfma16(wreg[kc], b1, acc1);
        }
        const u16* xb = h0f + (size_t)t*51200;
#pragma unroll
        for (int kc = 0; kc < 25; ++kc) {
            const int idx = hl*25 + kc;
            short8 a  = *(const short8*)&wihL[(p*50 + idx)*512 + l*8];
            short8 b0 = *(const short8*)(xb + idx*1024 + l*8);
            short8 b1 = *(const short8*)(xb + idx*1024 + 512 + l*8);
            acc0 = mfma16(a, b0, acc0);
            acc1 = mfma16(a, b1, acc1);
        }
        {
            const int mrow = (l>>4)*4, nn = l & 15;
#pragma unroll
            for (int r = 0; r < 4; ++r) {
                part[(((p*2+hl)*2 + 0)*16 + mrow + r)*16 + nn] = acc0[r];
                part[(((p*2+hl)*2 + 1)*16 + mrow + r)*16 + nn] = acc1[r];
            }
        }
        __syncthreads();

        float v[4];
#pragma unroll
        for (int g = 0; g < 4; ++g) {
            const int pp = g >> 1, m = (g & 1)*8 + ju;
            v[g] = part[(((pp*2+0)*2 + nt)*16 + m)*16 + n]
                 + part[(((pp*2+1)*2 + nt)*16 + m)*16 + n] + biasr[g];
        }
        float ig = 1.f/(1.f + expf(-v[0]));
        float fg = 1.f/(1.f + expf(-v[1]));
        float gg = tanhf(v[2]);
        float og = 1.f/(1.f + expf(-v[3]));
        float cn = fg * (*cp) + ig * gg;
        *cp = cn;
        float hn = og * tanhf(cn);
        hnxt[(kcj*2 + nt)*512 + llj*8 + iij] = f2bf(hn);
        hblk[ju*NB + b] = hn;
        __syncthreads();

        // per-block logit partials -> staging (no atomics)
        {
            float* stg = stage + (size_t)((d*2 + (s&1))*NCH + ch)*640;
            for (int kk = tid; kk < 640; kk += 256) {
                const int bb = kk / NU, uu = kk % NU;
                float sum = 0.f;
#pragma unroll
                for (int q = 0; q < 8; ++q) sum += lwc[q*NU + uu] * hblk[q*NB + bb];
                stg[kk] = sum;
            }
        }
        if (s > 0) reduce_stage(stage, logits2, d, ch, (s-1)&1, d ? (T_LEN-s) : (s-1), tid);

        dir_barrier(mybar, s, tid);
    }
    reduce_stage(stage, logits2, d, ch, 1, d ? 0 : (T_LEN-1), tid);
}

// ---- softmax over 20 logits -> alphabet sin/cos mix; store (cosP, sinP) ----
__global__ __launch_bounds__(256)
void epilogue(const float* __restrict__ logits2, const float* __restrict__ lin_b,
              const float* __restrict__ alphabet, float* __restrict__ cs)
{
    __shared__ float sa[NU*3], ca[NU*3], lb[NU];
    const int tid = threadIdx.x;
    if (tid < NU*3) { float al = alphabet[tid]; sa[tid] = sinf(al); ca[tid] = cosf(al); }
    if (tid < NU) lb[tid] = lin_b[tid];
    __syncthreads();
    const int row = blockIdx.x*256 + tid;   // t*NB + b
    if (row >= T_LEN*NB) return;
    const int t = row >> 5, b = row & 31;
    float lg[NU];
    float m = -1e30f;
#pragma unroll 4
    for (int u = 0; u < NU; ++u) {
        lg[u] = lb[u] + logits2[(size_t)t*640 + b*NU + u]
                      + logits2[((size_t)T_LEN + t)*640 + b*NU + u];
        m = fmaxf(m, lg[u]);
    }
    float ssum = 0.f;
#pragma unroll 4
    for (int u = 0; u < NU; ++u) { lg[u] = expf(lg[u] - m); ssum += lg[u]; }
    float inv = 1.f / ssum;
#pragma unroll
    for (int i = 0; i < 3; ++i) {
        float sv = 0.f, cv = 0.f;
#pragma unroll 4
        for (int u = 0; u < NU; ++u) {
            float sw = lg[u] * inv;
            sv += sw * sa[u*3 + i];
            cv += sw * ca[u*3 + i];
        }
        float rinv = rsqrtf(fmaxf(sv*sv + cv*cv, 1e-30f));
        *(float2*)(cs + ((size_t)row*3 + i)*2) = make_float2(cv*rinv, sv*rinv);
    }
}

// ---- sequential chain extension: one lane per molecule ----
__global__ __launch_bounds__(64)
void geometry(const float* __restrict__ cs, float* __restrict__ out)
{
    const int b = threadIdx.x;
    if (b >= NB) return;
    const float blen[3] = {1.329f, 1.459f, 1.525f};
    const float bang[3] = {2.034f, 2.119f, 1.937f};
    float sT[3], cT[3];
#pragma unroll
    for (int i = 0; i < 3; ++i) { sT[i] = sinf(bang[i]); cT[i] = cosf(bang[i]); }

    float Ax=0.f,Ay=0.f,Az=1.f, Bx=0.f,By=1.f,Bz=0.f, Cx=1.f,Cy=0.f,Cz=0.f;
    out[(0*NB + b)*3 + 0] = 0.f; out[(0*NB + b)*3 + 1] = 0.f; out[(0*NB + b)*3 + 2] = 1.f;
    out[(1*NB + b)*3 + 0] = 0.f; out[(1*NB + b)*3 + 1] = 1.f; out[(1*NB + b)*3 + 2] = 0.f;
    out[(2*NB + b)*3 + 0] = 1.f; out[(2*NB + b)*3 + 1] = 0.f; out[(2*NB + b)*3 + 2] = 0.f;

    for (int t = 1; t < T_LEN; ++t) {
        float2 pc[3];
#pragma unroll
        for (int i = 0; i < 3; ++i)
            pc[i] = *(const float2*)(cs + (((size_t)t*NB + b)*3 + i)*2);
#pragma unroll
        for (int i = 0; i < 3; ++i) {
            float R = blen[i];
            float d2x = -R*cT[i], d2y = R*pc[i].x*sT[i], d2z = R*pc[i].y*sT[i];
            float bcx = Cx-Bx, bcy = Cy-By, bcz = Cz-Bz;
            float inv = rsqrtf(bcx*bcx + bcy*bcy + bcz*bcz);
            bcx *= inv; bcy *= inv; bcz *= inv;
            float abx = Bx-Ax, aby = By-Ay, abz = Bz-Az;
            float nx = aby*bcz - abz*bcy;
            float ny = abz*bcx - abx*bcz;
            float nz = abx*bcy - aby*bcx;
            inv = rsqrtf(fmaxf(nx*nx + ny*ny + nz*nz, 1e-30f));
            nx *= inv; ny *= inv; nz *= inv;
            float mx = ny*bcz - nz*bcy;
            float my = nz*bcx - nx*bcz;
            float mz = nx*bcy - ny*bcx;
            float Dx = bcx*d2x + mx*d2y + nx*d2z + Cx;
            float Dy = bcy*d2x + my*d2y + ny*d2z + Cy;
            float Dz = bcz*d2x + mz*d2y + nz*d2z + Cz;
            Ax=Bx; Ay=By; Az=Bz; Bx=Cx; By=Cy; Bz=Cz; Cx=Dx; Cy=Dy; Cz=Dz;
            const int r = 3 + (t-1)*3 + i;
            out[((size_t)r*NB + b)*3 + 0] = Dx;
            out[((size_t)r*NB + b)*3 + 1] = Dy;
            out[((size_t)r*NB + b)*3 + 2] = Dz;
        }
    }
}

extern "C" void kernel_launch(void* const* d_in, const int* in_sizes, int n_in,
                              void* d_out, int out_size, void* d_ws, size_t ws_size,
                              hipStream_t stream)
{
    (void)in_sizes; (void)n_in; (void)out_size; (void)ws_size;
    const float* seq   = (const float*)d_in[0];
    const float* w_ih0 = (const float*)d_in[2];
    const float* w_hh0 = (const float*)d_in[3];
    const float* b0    = (const float*)d_in[4];
    const float* w_ih1 = (const float*)d_in[5];
    const float* w_hh1 = (const float*)d_in[6];
    const float* b1    = (const float*)d_in[7];
    const float* lin_w = (const float*)d_in[8];
    const float* lin_b = (const float*)d_in[9];
    const float* alpha = (const float*)d_in[10];

    // workspace layout (~57 MB total)
    char* ws = (char*)d_ws;
    size_t off = 0;
    u16* h0f   = (u16*)(ws + off); off += 52428800ull;   // [t][kc50][nt2][lane][i] bf16
    u16* hB    = (u16*)(ws + off); off += 204800ull;     // 2 bufs x 2 dirs x 25600 bf16
    float* c_st = (float*)(ws + off); off += 204800ull;  // cell state fp32
    int* barL0 = (int*)(ws + off); off += 4096ull;       // [d][s] arrival counters
    int* barL1 = (int*)(ws + off); off += 4096ull;
    float* stage = (float*)(ws + off); off += 1024000ull;   // [d][buf2][ch][640] logit partials
    float* logits2 = (float*)(ws + off); off += 2621440ull; // [d][t][b*20+u]
    float* cs = (float*)(ws + off); off += 393216ull;       // (cosP,sinP)

    // zero h/c state + both barrier arrays (contiguous)
    hipMemsetAsync(hB, 0, 204800 + 204800 + 4096 + 4096, stream);
    lstm0_persist<<<dim3(2*NCH), dim3(256), 0, stream>>>(seq, w_ih0, w_hh0, b0, h0f, hB, c_st, barL0);

    hipMemsetAsync(hB, 0, 204800 + 204800, stream);   // re-zero h/c for layer 1
    lstm1_persist<<<dim3(2*NCH), dim3(256), 0, stream>>>(w_ih1, w_hh1, b1, lin_w, h0f, hB, c_st,
                                                         barL1, stage, logits2);

    epilogue<<<dim3(64), dim3(256), 0, stream>>>(logits2, lin_b, alpha, cs);
    geometry<<<dim3(1), dim3(64), 0, stream>>>(cs, (float*)d_out);
}

// Round 5
// 14499.092 us; speedup vs baseline: 3.2902x; 3.2902x over previous
//
#include <hip/hip_runtime.h>
#include <math.h>

#define T_LEN 512
#define NB    32
#define EMB_  41
#define IN0_  42
#define HID_  800
#define G4_   3200
#define IN1_  1600
#define NU    20
#define NCH   100   // blocks per direction

typedef unsigned short u16;
typedef unsigned int   u32;
typedef unsigned long long u64;
typedef __attribute__((ext_vector_type(8))) short short8;
typedef __attribute__((ext_vector_type(4))) float f32x4;

union S8u { short8 s; u64 q[2]; };

__device__ __forceinline__ float bf2f(u16 v) {
    union { u32 u; float f; } c; c.u = ((u32)v) << 16; return c.f;
}
__device__ __forceinline__ u16 f2bf(float f) {
    union { float f; u32 u; } c; c.f = f;
    u32 r = (c.u + 0x7fffu + ((c.u >> 16) & 1u)) >> 16;
    return (u16)r;
}
__device__ __forceinline__ short cvt_hl(float v, int hl) {
    u16 hi = f2bf(v);
    return hl ? (short)f2bf(v - bf2f(hi)) : (short)hi;
}
__device__ __forceinline__ f32x4 mfma16(short8 a, short8 b, f32x4 c) {
    return __builtin_amdgcn_mfma_f32_16x16x32_bf16(a, b, c, 0, 0, 0);
}
__device__ __forceinline__ u64 aload(const u64* p) {
    return __hip_atomic_load(p, __ATOMIC_RELAXED, __HIP_MEMORY_SCOPE_AGENT);
}
__device__ __forceinline__ void astore(u64* p, u64 v) {
    __hip_atomic_store(p, v, __ATOMIC_RELAXED, __HIP_MEMORY_SCOPE_AGENT);
}

// Fence-free barrier among NCH co-resident blocks of one direction.
// __syncthreads() emits s_waitcnt vmcnt(0) before s_barrier, so this block's
// agent-scope (write-through) h stores are at the coherence point before the add.
__device__ __forceinline__ void dir_barrier(int* bar, int s, int tid) {
    __syncthreads();
    if (tid == 0) {
        __hip_atomic_fetch_add(&bar[s], 1, __ATOMIC_RELAXED, __HIP_MEMORY_SCOPE_AGENT);
        while (__hip_atomic_load(&bar[s], __ATOMIC_RELAXED, __HIP_MEMORY_SCOPE_AGENT) < NCH)
            __builtin_amdgcn_s_sleep(4);
    }
    __syncthreads();
}

// ---------------- Layer 0: persistent, 200 blocks x 256 threads ----------------
__global__ __launch_bounds__(256, 1)
void lstm0_persist(const float* __restrict__ seq, const float* __restrict__ wih0,
                   const float* __restrict__ whh0, const float* __restrict__ bias,
                   u16* __restrict__ h0f, u16* __restrict__ hB, float* __restrict__ c_st,
                   int* __restrict__ bar)
{
    __shared__ __align__(16) float part[2*2*2*16*16];   // 8 KB
    __shared__ __align__(16) float w0l[32*48];
    __shared__ __align__(16) float xsl[32*48];
    __shared__ u16 hpk[NB*8];
    const int tid = threadIdx.x;
    const int d = blockIdx.x / NCH, ch = blockIdx.x % NCH;
    const int w = tid >> 6, l = tid & 63;
    const int p = w & 1, hl = w >> 1;
    int* mybar = bar + d*T_LEN;

    short8 wreg[25];   // whh0 hi/lo A-frags, register-resident
    {
        const int m = l & 15, g = p*2 + (m>>3), j = ch*8 + (m&7);
        const float* base = whh0 + ((size_t)(d*G4_ + g*HID_ + j))*HID_ + (l>>4)*8;
#pragma unroll
        for (int kc = 0; kc < 25; ++kc) {
            float4 f0 = *(const float4*)(base + kc*32);
            float4 f1 = *(const float4*)(base + kc*32 + 4);
            short8 v;
            v[0]=cvt_hl(f0.x,hl); v[1]=cvt_hl(f0.y,hl); v[2]=cvt_hl(f0.z,hl); v[3]=cvt_hl(f0.w,hl);
            v[4]=cvt_hl(f1.x,hl); v[5]=cvt_hl(f1.y,hl); v[6]=cvt_hl(f1.z,hl); v[7]=cvt_hl(f1.w,hl);
            wreg[kc] = v;
        }
    }
    for (int idx = tid; idx < 32*EMB_; idx += 256) {
        int r = idx / EMB_, k = idx % EMB_;
        int ju_ = r >> 2, g = r & 3;
        w0l[r*48 + k] = wih0[((size_t)(d*G4_ + g*HID_ + ch*8 + ju_))*IN0_ + k];
    }
    const int ju = tid >> 5, b = tid & 31;
    const int j = ch*8 + ju;
    const int nt = b >> 4, n = b & 15;
    float biasr[4], wpos[4];
#pragma unroll
    for (int g = 0; g < 4; ++g) {
        biasr[g] = bias[d*G4_ + g*HID_ + j];
        wpos[g]  = wih0[((size_t)(d*G4_ + g*HID_ + j))*IN0_ + EMB_];
    }
    float* cp = c_st + (size_t)(d*NB + b)*HID_ + j;
    __syncthreads();

    for (int s = 0; s < T_LEN; ++s) {
        const int t = d ? (T_LEN-1-s) : s;
        const u64* hq = (const u64*)(hB + (size_t)((s&1)*2 + d)*25600);
        u64*       hnq = (u64*)(hB + (size_t)(((s&1)^1)*2 + d)*25600);

        f32x4 acc0 = {0.f,0.f,0.f,0.f}, acc1 = {0.f,0.f,0.f,0.f};
#pragma unroll 5
        for (int kc = 0; kc < 25; ++kc) {
            S8u b0, b1;
            b0.q[0] = aload(hq + kc*256 +       l*2);
            b0.q[1] = aload(hq + kc*256 +       l*2 + 1);
            b1.q[0] = aload(hq + kc*256 + 128 + l*2);
            b1.q[1] = aload(hq + kc*256 + 128 + l*2 + 1);
            acc0 = mfma16(wreg[kc], b0.s, acc0);
            acc1 = mfma16(wreg[kc], b1.s, acc1);
        }
        {
            const int mrow = (l>>4)*4, nn = l & 15;
#pragma unroll
            for (int r = 0; r < 4; ++r) {
                part[(((p*2+hl)*2 + 0)*16 + mrow + r)*16 + nn] = acc0[r];
                part[(((p*2+hl)*2 + 1)*16 + mrow + r)*16 + nn] = acc1[r];
            }
        }
        for (int idx = tid; idx < 32*EMB_; idx += 256)
            xsl[(idx/EMB_)*48 + idx%EMB_] = seq[(size_t)t*(NB*EMB_) + idx];
        __syncthreads();

        float dot0 = 0.f, dot1 = 0.f, dot2 = 0.f, dot3 = 0.f;
        {
            const float* wr = &w0l[ju*4*48];
            const float* xr = &xsl[b*48];
#pragma unroll
            for (int k4 = 0; k4 < 40; k4 += 4) {
                float4 xk = *(const float4*)(xr + k4);
                float4 w0 = *(const float4*)(wr + 0*48 + k4);
                float4 w1 = *(const float4*)(wr + 1*48 + k4);
                float4 w2 = *(const float4*)(wr + 2*48 + k4);
                float4 w3 = *(const float4*)(wr + 3*48 + k4);
                dot0 += w0.x*xk.x + w0.y*xk.y + w0.z*xk.z + w0.w*xk.w;
                dot1 += w1.x*xk.x + w1.y*xk.y + w1.z*xk.z + w1.w*xk.w;
                dot2 += w2.x*xk.x + w2.y*xk.y + w2.z*xk.z + w2.w*xk.w;
                dot3 += w3.x*xk.x + w3.y*xk.y + w3.z*xk.z + w3.w*xk.w;
            }
            float xk = xr[40];
            dot0 += wr[0*48+40]*xk; dot1 += wr[1*48+40]*xk;
            dot2 += wr[2*48+40]*xk; dot3 += wr[3*48+40]*xk;
        }
        float v[4] = {dot0, dot1, dot2, dot3};
#pragma unroll
        for (int g = 0; g < 4; ++g) {
            const int pp = g >> 1, m = (g & 1)*8 + ju;
            v[g] += part[(((pp*2+0)*2 + nt)*16 + m)*16 + n]
                  + part[(((pp*2+1)*2 + nt)*16 + m)*16 + n]
                  + biasr[g] + (float)t * wpos[g];
        }
        float ig = 1.f/(1.f + expf(-v[0]));
        float fg = 1.f/(1.f + expf(-v[1]));
        float gg = tanhf(v[2]);
        float og = 1.f/(1.f + expf(-v[3]));
        float cn = fg * (*cp) + ig * gg;
        *cp = cn;
        hpk[b*8 + ju] = f2bf(og * tanhf(cn));
        __syncthreads();

        if (tid < 64) {
            const int bb = tid >> 1, half = tid & 1;
            const u16* hp = &hpk[bb*8 + half*4];
            u64 pk = (u64)hp[0] | ((u64)hp[1]<<16) | ((u64)hp[2]<<32) | ((u64)hp[3]<<48);
            const int ntb = bb >> 4, llb = ((ch&3)<<4) | (bb&15);
            astore(hnq + ((ch>>2)*2 + ntb)*128 + llb*2 + half, pk);    // next-step h (coherent)
            u64* xq = (u64*)(h0f + (size_t)t*51200);                   // cross-dispatch, plain
            xq[((d*25 + (ch>>2))*2 + ntb)*128 + llb*2 + half] = pk;
        }
        dir_barrier(mybar, s, tid);
    }
}

// ---------------- Layer 1: persistent; fused x-GEMM + final linear ----------------
__global__ __launch_bounds__(256, 1)
void lstm1_persist(const float* __restrict__ wih1, const float* __restrict__ whh1,
                   const float* __restrict__ bias, const float* __restrict__ lin_w,
                   const u16* __restrict__ h0f, u16* __restrict__ hB, float* __restrict__ c_st,
                   int* __restrict__ bar, float* __restrict__ logits)
{
    __shared__ __align__(16) float part[2*2*2*16*16];   // 8 KB
    __shared__ __align__(16) u16  wihL[2*50*512];       // 100 KB w_ih1 A-frags
    __shared__ float lwc[8*NU];
    __shared__ float hblk[8*NB];
    __shared__ u16 hpk[NB*8];
    const int tid = threadIdx.x;
    const int d = blockIdx.x / NCH, ch = blockIdx.x % NCH;
    const int w = tid >> 6, l = tid & 63;
    const int p = w & 1, hl = w >> 1;
    int* mybar = bar + d*T_LEN;

    short8 wreg[25];
    {
        const int m = l & 15, g = p*2 + (m>>3), j = ch*8 + (m&7);
        const float* base = whh1 + ((size_t)(d*G4_ + g*HID_ + j))*HID_ + (l>>4)*8;
#pragma unroll
        for (int kc = 0; kc < 25; ++kc) {
            float4 f0 = *(const float4*)(base + kc*32);
            float4 f1 = *(const float4*)(base + kc*32 + 4);
            short8 v;
            v[0]=cvt_hl(f0.x,hl); v[1]=cvt_hl(f0.y,hl); v[2]=cvt_hl(f0.z,hl); v[3]=cvt_hl(f0.w,hl);
            v[4]=cvt_hl(f1.x,hl); v[5]=cvt_hl(f1.y,hl); v[6]=cvt_hl(f1.z,hl); v[7]=cvt_hl(f1.w,hl);
            wreg[kc] = v;
        }
    }
    for (int o = tid; o < 6400; o += 256) {
        int pp = o / 3200, r = o % 3200, kc = r >> 6, ll = r & 63;
        int m = ll & 15, g = pp*2 + (m>>3), jj = ch*8 + (m&7);
        const float* base = wih1 + ((size_t)(d*G4_ + g*HID_ + jj))*IN1_ + kc*32 + (ll>>4)*8;
        float4 f0 = *(const float4*)base;
        float4 f1 = *(const float4*)(base + 4);
        short8 v;
        v[0]=(short)f2bf(f0.x); v[1]=(short)f2bf(f0.y); v[2]=(short)f2bf(f0.z); v[3]=(short)f2bf(f0.w);
        v[4]=(short)f2bf(f1.x); v[5]=(short)f2bf(f1.y); v[6]=(short)f2bf(f1.z); v[7]=(short)f2bf(f1.w);
        *(short8*)&wihL[o*8] = v;
    }
    if (tid < 8*NU) {
        int jju = tid / NU, u = tid % NU;
        lwc[tid] = lin_w[(size_t)u*IN1_ + d*HID_ + ch*8 + jju];
    }
    const int ju = tid >> 5, b = tid & 31;
    const int j = ch*8 + ju;
    const int nt = b >> 4, n = b & 15;
    float biasr[4];
#pragma unroll
    for (int g = 0; g < 4; ++g) biasr[g] = bias[d*G4_ + g*HID_ + j];
    float* cp = c_st + (size_t)(d*NB + b)*HID_ + j;
    __syncthreads();

    for (int s = 0; s < T_LEN; ++s) {
        const int t = d ? (T_LEN-1-s) : s;
        const u64* hq = (const u64*)(hB + (size_t)((s&1)*2 + d)*25600);
        u64*       hnq = (u64*)(hB + (size_t)(((s&1)^1)*2 + d)*25600);

        f32x4 acc0 = {0.f,0.f,0.f,0.f}, acc1 = {0.f,0.f,0.f,0.f};
#pragma unroll 5
        for (int kc = 0; kc < 25; ++kc) {
            S8u b0, b1;
            b0.q[0] = aload(hq + kc*256 +       l*2);
            b0.q[1] = aload(hq + kc*256 +       l*2 + 1);
            b1.q[0] = aload(hq + kc*256 + 128 + l*2);
            b1.q[1] = aload(hq + kc*256 + 128 + l*2 + 1);
            acc0 = mfma16(wreg[kc], b0.s, acc0);
            acc1 = mfma16(wreg[kc], b1.s, acc1);
        }
        const u16* xb = h0f + (size_t)t*51200;     // written by L0 dispatch: plain loads
#pragma unroll 5
        for (int kc = 0; kc < 25; ++kc) {
            const int idx = hl*25 + kc;
            short8 a  = *(const short8*)&wihL[(p*50 + idx)*512 + l*8];
            short8 b0 = *(const short8*)(xb + idx*1024 + l*8);
            short8 b1 = *(const short8*)(xb + idx*1024 + 512 + l*8);
            acc0 = mfma16(a, b0, acc0);
            acc1 = mfma16(a, b1, acc1);
        }
        {
            const int mrow = (l>>4)*4, nn = l & 15;
#pragma unroll
            for (int r = 0; r < 4; ++r) {
                part[(((p*2+hl)*2 + 0)*16 + mrow + r)*16 + nn] = acc0[r];
                part[(((p*2+hl)*2 + 1)*16 + mrow + r)*16 + nn] = acc1[r];
            }
        }
        __syncthreads();

        float v[4];
#pragma unroll
        for (int g = 0; g < 4; ++g) {
            const int pp = g >> 1, m = (g & 1)*8 + ju;
            v[g] = part[(((pp*2+0)*2 + nt)*16 + m)*16 + n]
                 + part[(((pp*2+1)*2 + nt)*16 + m)*16 + n] + biasr[g];
        }
        float ig = 1.f/(1.f + expf(-v[0]));
        float fg = 1.f/(1.f + expf(-v[1]));
        float gg = tanhf(v[2]);
        float og = 1.f/(1.f + expf(-v[3]));
        float cn = fg * (*cp) + ig * gg;
        *cp = cn;
        float hn = og * tanhf(cn);
        hblk[ju*NB + b] = hn;
        hpk[b*8 + ju] = f2bf(hn);
        __syncthreads();

        if (tid < 64) {
            const int bb = tid >> 1, half = tid & 1;
            const u16* hp = &hpk[bb*8 + half*4];
            u64 pk = (u64)hp[0] | ((u64)hp[1]<<16) | ((u64)hp[2]<<32) | ((u64)hp[3]<<48);
            const int ntb = bb >> 4, llb = ((ch&3)<<4) | (bb&15);
            astore(hnq + ((ch>>2)*2 + ntb)*128 + llb*2 + half, pk);
        }
        // fused final linear: per-block partials -> global coherent atomics
        {
            float* lg = logits + (size_t)t*(NB*NU);
            for (int q = tid; q < NB*NU; q += 256) {
                int kk = q + (ch & 31)*NU;          // rotate start to spread contention
                if (kk >= NB*NU) kk -= NB*NU;
                const int bb = kk / NU, uu = kk % NU;
                float sum = 0.f;
#pragma unroll
                for (int qq = 0; qq < 8; ++qq) sum += lwc[qq*NU + uu] * hblk[qq*NB + bb];
                atomicAdd(lg + kk, sum);
            }
        }
        dir_barrier(mybar, s, tid);
    }
}

__global__ __launch_bounds__(256) void logits_init(const float* __restrict__ lb, float* __restrict__ logits)
{
    int idx = blockIdx.x * 256 + threadIdx.x;
    if (idx < T_LEN*NB*NU) logits[idx] = lb[idx % NU];
}

// ---- softmax over 20 logits -> alphabet sin/cos mix; store (cosP, sinP) ----
__global__ __launch_bounds__(256)
void epilogue(const float* __restrict__ logits, const float* __restrict__ alphabet,
              float* __restrict__ cs)
{
    __shared__ float sa[NU*3], ca[NU*3];
    const int tid = threadIdx.x;
    if (tid < NU*3) { float al = alphabet[tid]; sa[tid] = sinf(al); ca[tid] = cosf(al); }
    __syncthreads();
    const int row = blockIdx.x*256 + tid;   // t*NB + b
    if (row >= T_LEN*NB) return;
    float lg[NU];
    float m = -1e30f;
#pragma unroll 4
    for (int u = 0; u < NU; ++u) { lg[u] = logits[(size_t)row*NU + u]; m = fmaxf(m, lg[u]); }
    float ssum = 0.f;
#pragma unroll 4
    for (int u = 0; u < NU; ++u) { lg[u] = expf(lg[u] - m); ssum += lg[u]; }
    float inv = 1.f / ssum;
#pragma unroll
    for (int i = 0; i < 3; ++i) {
        float sv = 0.f, cv = 0.f;
#pragma unroll 4
        for (int u = 0; u < NU; ++u) {
            float sw = lg[u] * inv;
            sv += sw * sa[u*3 + i];
            cv += sw * ca[u*3 + i];
        }
        float rinv = rsqrtf(fmaxf(sv*sv + cv*cv, 1e-30f));
        *(float2*)(cs + ((size_t)row*3 + i)*2) = make_float2(cv*rinv, sv*rinv);
    }
}

// ---- sequential chain extension: one lane per molecule ----
__global__ __launch_bounds__(64)
void geometry(const float* __restrict__ cs, float* __restrict__ out)
{
    const int b = threadIdx.x;
    if (b >= NB) return;
    const float blen[3] = {1.329f, 1.459f, 1.525f};
    const float bang[3] = {2.034f, 2.119f, 1.937f};
    float sT[3], cT[3];
#pragma unroll
    for (int i = 0; i < 3; ++i) { sT[i] = sinf(bang[i]); cT[i] = cosf(bang[i]); }

    float Ax=0.f,Ay=0.f,Az=1.f, Bx=0.f,By=1.f,Bz=0.f, Cx=1.f,Cy=0.f,Cz=0.f;
    out[(0*NB + b)*3 + 0] = 0.f; out[(0*NB + b)*3 + 1] = 0.f; out[(0*NB + b)*3 + 2] = 1.f;
    out[(1*NB + b)*3 + 0] = 0.f; out[(1*NB + b)*3 + 1] = 1.f; out[(1*NB + b)*3 + 2] = 0.f;
    out[(2*NB + b)*3 + 0] = 1.f; out[(2*NB + b)*3 + 1] = 0.f; out[(2*NB + b)*3 + 2] = 0.f;

    for (int t = 1; t < T_LEN; ++t) {
        float2 pc[3];
#pragma unroll
        for (int i = 0; i < 3; ++i)
            pc[i] = *(const float2*)(cs + (((size_t)t*NB + b)*3 + i)*2);
#pragma unroll
        for (int i = 0; i < 3; ++i) {
            float R = blen[i];
            float d2x = -R*cT[i], d2y = R*pc[i].x*sT[i], d2z = R*pc[i].y*sT[i];
            float bcx = Cx-Bx, bcy = Cy-By, bcz = Cz-Bz;
            float inv = rsqrtf(bcx*bcx + bcy*bcy + bcz*bcz);
            bcx *= inv; bcy *= inv; bcz *= inv;
            float abx = Bx-Ax, aby = By-Ay, abz = Bz-Az;
            float nx = aby*bcz - abz*bcy;
            float ny = abz*bcx - abx*bcz;
            float nz = abx*bcy - aby*bcx;
            inv = rsqrtf(fmaxf(nx*nx + ny*ny + nz*nz, 1e-30f));
            nx *= inv; ny *= inv; nz *= inv;
            float mx = ny*bcz - nz*bcy;
            float my = nz*bcx - nx*bcz;
            float mz = nx*bcy - ny*bcx;
            float Dx = bcx*d2x + mx*d2y + nx*d2z + Cx;
            float Dy = bcy*d2x + my*d2y + ny*d2z + Cy;
            float Dz = bcz*d2x + mz*d2y + nz*d2z + Cz;
            Ax=Bx; Ay=By; Az=Bz; Bx=Cx; By=Cy; Bz=Cz; Cx=Dx; Cy=Dy; Cz=Dz;
            const int r = 3 + (t-1)*3 + i;
            out[((size_t)r*NB + b)*3 + 0] = Dx;
            out[((size_t)r*NB + b)*3 + 1] = Dy;
            out[((size_t)r*NB + b)*3 + 2] = Dz;
        }
    }
}

extern "C" void kernel_launch(void* const* d_in, const int* in_sizes, int n_in,
                              void* d_out, int out_size, void* d_ws, size_t ws_size,
                              hipStream_t stream)
{
    (void)in_sizes; (void)n_in; (void)out_size; (void)ws_size;
    const float* seq   = (const float*)d_in[0];
    const float* w_ih0 = (const float*)d_in[2];
    const float* w_hh0 = (const float*)d_in[3];
    const float* b0    = (const float*)d_in[4];
    const float* w_ih1 = (const float*)d_in[5];
    const float* w_hh1 = (const float*)d_in[6];
    const float* b1    = (const float*)d_in[7];
    const float* lin_w = (const float*)d_in[8];
    const float* lin_b = (const float*)d_in[9];
    const float* alpha = (const float*)d_in[10];

    // workspace (~54.5 MB)
    char* ws = (char*)d_ws;
    size_t off = 0;
    u16* h0f   = (u16*)(ws + off); off += 52428800ull;   // [t][kc50][nt2][lane][i] bf16
    u16* hB    = (u16*)(ws + off); off += 204800ull;     // 2 bufs x 2 dirs x 25600 bf16
    float* c_st = (float*)(ws + off); off += 204800ull;
    int* barL0 = (int*)(ws + off); off += 4096ull;
    int* barL1 = (int*)(ws + off); off += 4096ull;
    float* logits = (float*)(ws + off); off += 1310720ull;  // [t][b][u] fp32
    float* cs = (float*)(ws + off); off += 393216ull;

    hipMemsetAsync(hB, 0, 204800 + 204800 + 4096 + 4096, stream);   // hB+c_st+both bars
    logits_init<<<dim3(1280), dim3(256), 0, stream>>>(lin_b, logits);

    lstm0_persist<<<dim3(2*NCH), dim3(256), 0, stream>>>(seq, w_ih0, w_hh0, b0, h0f, hB, c_st, barL0);

    hipMemsetAsync(hB, 0, 204800 + 204800, stream);   // re-zero h/c for layer 1
    lstm1_persist<<<dim3(2*NCH), dim3(256), 0, stream>>>(w_ih1, w_hh1, b1, lin_w, h0f, hB, c_st,
                                                         barL1, logits);

    epilogue<<<dim3(64), dim3(256), 0, stream>>>(logits, alpha, cs);
    geometry<<<dim3(1), dim3(64), 0, stream>>>(cs, (float*)d_out);
}

// Round 6
// 10864.500 us; speedup vs baseline: 4.3909x; 1.3345x over previous
//
#include <hip/hip_runtime.h>
#include <math.h>

#define T_LEN 512
#define NB    32
#define EMB_  41
#define IN0_  42
#define HID_  800
#define G4_   3200
#define IN1_  1600
#define NU    20
#define NCH   100   // blocks per direction

typedef unsigned short u16;
typedef unsigned int   u32;
typedef unsigned long long u64;
typedef __attribute__((ext_vector_type(8))) short short8;
typedef __attribute__((ext_vector_type(4))) float f32x4;

__device__ __forceinline__ float bf2f(u16 v) {
    union { u32 u; float f; } c; c.u = ((u32)v) << 16; return c.f;
}
__device__ __forceinline__ u16 f2bf(float f) {
    union { float f; u32 u; } c; c.f = f;
    u32 r = (c.u + 0x7fffu + ((c.u >> 16) & 1u)) >> 16;
    return (u16)r;
}
__device__ __forceinline__ short cvt_hl(float v, int hl) {
    u16 hi = f2bf(v);
    return hl ? (short)f2bf(v - bf2f(hi)) : (short)hi;
}
__device__ __forceinline__ f32x4 mfma16(short8 a, short8 b, f32x4 c) {
    return __builtin_amdgcn_mfma_f32_16x16x32_bf16(a, b, c, 0, 0, 0);
}
__device__ __forceinline__ u64 aload(const u64* p) {
    return __hip_atomic_load(p, __ATOMIC_RELAXED, __HIP_MEMORY_SCOPE_AGENT);
}
__device__ __forceinline__ void astore(u64* p, u64 v) {
    __hip_atomic_store(p, v, __ATOMIC_RELAXED, __HIP_MEMORY_SCOPE_AGENT);
}
__device__ __forceinline__ int afload(const int* p) {
    return __hip_atomic_load(p, __ATOMIC_RELAXED, __HIP_MEMORY_SCOPE_AGENT);
}
__device__ __forceinline__ void afstore(int* p, int v) {
    __hip_atomic_store(p, v, __ATOMIC_RELAXED, __HIP_MEMORY_SCOPE_AGENT);
}

// ---------------- Layer 0: persistent, 200 blocks x 256 threads ----------------
// Distributed flag barrier: block (d,ch) owns flags[(d*NCH+ch)*16]; consumer thread
// tid<NCH spins on producer tid's flag. h-exchange staged once per block into LDS.
__global__ __launch_bounds__(256, 1)
void lstm0_persist(const float* __restrict__ seq, const float* __restrict__ wih0,
                   const float* __restrict__ whh0, const float* __restrict__ bias,
                   u16* __restrict__ h0f, u16* __restrict__ hB, int* __restrict__ flags)
{
    __shared__ __align__(16) float part[2048];          // 8 KB
    __shared__ __align__(16) u16 stageB[25600];         // 51.2 KB h-slab stage
    __shared__ __align__(16) float w0l[32*48];          // 6 KB
    __shared__ __align__(16) float xsl[32*48];          // 6 KB
    __shared__ u16 hpk[NB*8];
    const int tid = threadIdx.x;
    const int d = blockIdx.x / NCH, ch = blockIdx.x % NCH;
    const int w = tid >> 6, l = tid & 63;
    const int p = w & 1, hl = w >> 1;
    int* myflags = flags + d*NCH*16;

    short8 wreg[25];   // whh0 hi/lo A-frags, register-resident
    {
        const int m = l & 15, g = p*2 + (m>>3), j = ch*8 + (m&7);
        const float* base = whh0 + ((size_t)(d*G4_ + g*HID_ + j))*HID_ + (l>>4)*8;
#pragma unroll
        for (int kc = 0; kc < 25; ++kc) {
            float4 f0 = *(const float4*)(base + kc*32);
            float4 f1 = *(const float4*)(base + kc*32 + 4);
            short8 v;
            v[0]=cvt_hl(f0.x,hl); v[1]=cvt_hl(f0.y,hl); v[2]=cvt_hl(f0.z,hl); v[3]=cvt_hl(f0.w,hl);
            v[4]=cvt_hl(f1.x,hl); v[5]=cvt_hl(f1.y,hl); v[6]=cvt_hl(f1.z,hl); v[7]=cvt_hl(f1.w,hl);
            wreg[kc] = v;
        }
    }
    for (int idx = tid; idx < 32*EMB_; idx += 256) {
        int r = idx / EMB_, k = idx % EMB_;
        int ju_ = r >> 2, g = r & 3;
        w0l[r*48 + k] = wih0[((size_t)(d*G4_ + g*HID_ + ch*8 + ju_))*IN0_ + k];
    }
    const int ju = tid >> 5, b = tid & 31;
    const int j = ch*8 + ju;
    const int nt = b >> 4, n = b & 15;
    float biasr[4], wpos[4];
#pragma unroll
    for (int g = 0; g < 4; ++g) {
        biasr[g] = bias[d*G4_ + g*HID_ + j];
        wpos[g]  = wih0[((size_t)(d*G4_ + g*HID_ + j))*IN0_ + EMB_];
    }
    float creg = 0.f;
    __syncthreads();

    for (int s = 0; s < T_LEN; ++s) {
        const int t = d ? (T_LEN-1-s) : s;
        const u64* hq64 = (const u64*)(hB + (size_t)((s&1)*2 + d)*25600);
        u64*      hnq  = (u64*)(hB + (size_t)(((s&1)^1)*2 + d)*25600);

        if (s > 0 && tid < NCH)
            while (afload(myflags + tid*16) < s) __builtin_amdgcn_s_sleep(1);
        __syncthreads();

        {   // stage the 51.2 KB B-slab once per block
            u64 tmp[25];
#pragma unroll
            for (int q = 0; q < 25; ++q) tmp[q] = aload(hq64 + tid + q*256);
#pragma unroll
            for (int q = 0; q < 25; ++q) ((u64*)stageB)[tid + q*256] = tmp[q];
        }
        for (int idx = tid; idx < 32*EMB_; idx += 256)
            xsl[(idx/EMB_)*48 + idx%EMB_] = seq[(size_t)t*(NB*EMB_) + idx];
        __syncthreads();

        f32x4 acc0 = {0.f,0.f,0.f,0.f}, acc1 = {0.f,0.f,0.f,0.f};
#pragma unroll 5
        for (int kc = 0; kc < 25; ++kc) {
            short8 b0 = *(const short8*)(stageB + kc*1024 + l*8);
            short8 b1 = *(const short8*)(stageB + kc*1024 + 512 + l*8);
            acc0 = mfma16(wreg[kc], b0, acc0);
            acc1 = mfma16(wreg[kc], b1, acc1);
        }
        {
            const int mrow = (l>>4)*4, nn = l & 15;
#pragma unroll
            for (int r = 0; r < 4; ++r) {
                part[(((p*2+hl)*2 + 0)*16 + mrow + r)*16 + nn] = acc0[r];
                part[(((p*2+hl)*2 + 1)*16 + mrow + r)*16 + nn] = acc1[r];
            }
        }
        __syncthreads();

        float dot0 = 0.f, dot1 = 0.f, dot2 = 0.f, dot3 = 0.f;
        {
            const float* wr = &w0l[ju*4*48];
            const float* xr = &xsl[b*48];
#pragma unroll
            for (int k4 = 0; k4 < 40; k4 += 4) {
                float4 xk = *(const float4*)(xr + k4);
                float4 w0 = *(const float4*)(wr + 0*48 + k4);
                float4 w1 = *(const float4*)(wr + 1*48 + k4);
                float4 w2 = *(const float4*)(wr + 2*48 + k4);
                float4 w3 = *(const float4*)(wr + 3*48 + k4);
                dot0 += w0.x*xk.x + w0.y*xk.y + w0.z*xk.z + w0.w*xk.w;
                dot1 += w1.x*xk.x + w1.y*xk.y + w1.z*xk.z + w1.w*xk.w;
                dot2 += w2.x*xk.x + w2.y*xk.y + w2.z*xk.z + w2.w*xk.w;
                dot3 += w3.x*xk.x + w3.y*xk.y + w3.z*xk.z + w3.w*xk.w;
            }
            float xk = xr[40];
            dot0 += wr[0*48+40]*xk; dot1 += wr[1*48+40]*xk;
            dot2 += wr[2*48+40]*xk; dot3 += wr[3*48+40]*xk;
        }
        float v[4] = {dot0, dot1, dot2, dot3};
#pragma unroll
        for (int g = 0; g < 4; ++g) {
            const int pp = g >> 1, m = (g & 1)*8 + ju;
            v[g] += part[(((pp*2+0)*2 + nt)*16 + m)*16 + n]
                  + part[(((pp*2+1)*2 + nt)*16 + m)*16 + n]
                  + biasr[g] + (float)t * wpos[g];
        }
        float ig = 1.f/(1.f + expf(-v[0]));
        float fg = 1.f/(1.f + expf(-v[1]));
        float gg = tanhf(v[2]);
        float og = 1.f/(1.f + expf(-v[3]));
        creg = fg * creg + ig * gg;
        hpk[b*8 + ju] = f2bf(og * tanhf(creg));
        __syncthreads();

        if (tid < 64) {
            const int bb = tid >> 1, half = tid & 1;
            const u16* hp = &hpk[bb*8 + half*4];
            u64 pk = (u64)hp[0] | ((u64)hp[1]<<16) | ((u64)hp[2]<<32) | ((u64)hp[3]<<48);
            const int ntb = bb >> 4, llb = ((ch&3)<<4) | (bb&15);
            astore(hnq + ((ch>>2)*2 + ntb)*128 + llb*2 + half, pk);    // next-step h
            u64* xq = (u64*)(h0f + (size_t)t*51200);                   // cross-dispatch
            xq[((d*25 + (ch>>2))*2 + ntb)*128 + llb*2 + half] = pk;
        }
        __syncthreads();                       // drains vmcnt: h stores at coherence point
        if (tid == 0) afstore(myflags + ch*16, s+1);
    }
}

// ---------------- Layer 1: persistent; fused x-GEMM + final linear ----------------
__global__ __launch_bounds__(256, 1)
void lstm1_persist(const float* __restrict__ wih1, const float* __restrict__ whh1,
                   const float* __restrict__ bias, const float* __restrict__ lin_w,
                   const u16* __restrict__ h0f, u16* __restrict__ hB,
                   int* __restrict__ flags, float* __restrict__ logits)
{
    __shared__ __align__(16) u16 wihL[2*50*512];        // 100 KB w_ih1 A-frags
    __shared__ __align__(16) u16 stageB[25600];         // 51.2 KB; part aliases first 8 KB
    __shared__ float lwc[8*NU];
    __shared__ float hblk[8*NB];
    __shared__ u16 hpk[NB*8];
    float* part = (float*)stageB;                       // 2048 floats, reused after MFMA
    const int tid = threadIdx.x;
    const int d = blockIdx.x / NCH, ch = blockIdx.x % NCH;
    const int w = tid >> 6, l = tid & 63;
    const int p = w & 1, hl = w >> 1;
    int* myflags = flags + d*NCH*16;

    short8 wreg[25];
    {
        const int m = l & 15, g = p*2 + (m>>3), j = ch*8 + (m&7);
        const float* base = whh1 + ((size_t)(d*G4_ + g*HID_ + j))*HID_ + (l>>4)*8;
#pragma unroll
        for (int kc = 0; kc < 25; ++kc) {
            float4 f0 = *(const float4*)(base + kc*32);
            float4 f1 = *(const float4*)(base + kc*32 + 4);
            short8 v;
            v[0]=cvt_hl(f0.x,hl); v[1]=cvt_hl(f0.y,hl); v[2]=cvt_hl(f0.z,hl); v[3]=cvt_hl(f0.w,hl);
            v[4]=cvt_hl(f1.x,hl); v[5]=cvt_hl(f1.y,hl); v[6]=cvt_hl(f1.z,hl); v[7]=cvt_hl(f1.w,hl);
            wreg[kc] = v;
        }
    }
    for (int o = tid; o < 6400; o += 256) {
        int pp = o / 3200, r = o % 3200, kc = r >> 6, ll = r & 63;
        int m = ll & 15, g = pp*2 + (m>>3), jj = ch*8 + (m&7);
        const float* base = wih1 + ((size_t)(d*G4_ + g*HID_ + jj))*IN1_ + kc*32 + (ll>>4)*8;
        float4 f0 = *(const float4*)base;
        float4 f1 = *(const float4*)(base + 4);
        short8 v;
        v[0]=(short)f2bf(f0.x); v[1]=(short)f2bf(f0.y); v[2]=(short)f2bf(f0.z); v[3]=(short)f2bf(f0.w);
        v[4]=(short)f2bf(f1.x); v[5]=(short)f2bf(f1.y); v[6]=(short)f2bf(f1.z); v[7]=(short)f2bf(f1.w);
        *(short8*)&wihL[o*8] = v;
    }
    if (tid < 8*NU) {
        int jju = tid / NU, u = tid % NU;
        lwc[tid] = lin_w[(size_t)u*IN1_ + d*HID_ + ch*8 + jju];
    }
    const int ju = tid >> 5, b = tid & 31;
    const int j = ch*8 + ju;
    const int nt = b >> 4, n = b & 15;
    float biasr[4];
#pragma unroll
    for (int g = 0; g < 4; ++g) biasr[g] = bias[d*G4_ + g*HID_ + j];
    float creg = 0.f;
    __syncthreads();

    for (int s = 0; s < T_LEN; ++s) {
        const int t = d ? (T_LEN-1-s) : s;
        const u64* hq64 = (const u64*)(hB + (size_t)((s&1)*2 + d)*25600);
        u64*      hnq  = (u64*)(hB + (size_t)(((s&1)^1)*2 + d)*25600);

        if (s > 0 && tid < NCH)
            while (afload(myflags + tid*16) < s) __builtin_amdgcn_s_sleep(1);
        __syncthreads();

        {
            u64 tmp[25];
#pragma unroll
            for (int q = 0; q < 25; ++q) tmp[q] = aload(hq64 + tid + q*256);
#pragma unroll
            for (int q = 0; q < 25; ++q) ((u64*)stageB)[tid + q*256] = tmp[q];
        }
        __syncthreads();

        f32x4 acc0 = {0.f,0.f,0.f,0.f}, acc1 = {0.f,0.f,0.f,0.f};
#pragma unroll 5
        for (int kc = 0; kc < 25; ++kc) {
            short8 b0 = *(const short8*)(stageB + kc*1024 + l*8);
            short8 b1 = *(const short8*)(stageB + kc*1024 + 512 + l*8);
            acc0 = mfma16(wreg[kc], b0, acc0);
            acc1 = mfma16(wreg[kc], b1, acc1);
        }
        const u16* xb = h0f + (size_t)t*51200;
#pragma unroll 5
        for (int kc = 0; kc < 25; ++kc) {
            const int idx = hl*25 + kc;
            short8 a  = *(const short8*)&wihL[(p*50 + idx)*512 + l*8];
            short8 b0 = *(const short8*)(xb + idx*1024 + l*8);
            short8 b1 = *(const short8*)(xb + idx*1024 + 512 + l*8);
            acc0 = mfma16(a, b0, acc0);
            acc1 = mfma16(a, b1, acc1);
        }
        __syncthreads();                      // all stageB reads done; part may alias
        {
            const int mrow = (l>>4)*4, nn = l & 15;
#pragma unroll
            for (int r = 0; r < 4; ++r) {
                part[(((p*2+hl)*2 + 0)*16 + mrow + r)*16 + nn] = acc0[r];
                part[(((p*2+hl)*2 + 1)*16 + mrow + r)*16 + nn] = acc1[r];
            }
        }
        __syncthreads();

        float v[4];
#pragma unroll
        for (int g = 0; g < 4; ++g) {
            const int pp = g >> 1, m = (g & 1)*8 + ju;
            v[g] = part[(((pp*2+0)*2 + nt)*16 + m)*16 + n]
                 + part[(((pp*2+1)*2 + nt)*16 + m)*16 + n] + biasr[g];
        }
        float ig = 1.f/(1.f + expf(-v[0]));
        float fg = 1.f/(1.f + expf(-v[1]));
        float gg = tanhf(v[2]);
        float og = 1.f/(1.f + expf(-v[3]));
        creg = fg * creg + ig * gg;
        float hn = og * tanhf(creg);
        hblk[ju*NB + b] = hn;
        hpk[b*8 + ju] = f2bf(hn);
        __syncthreads();

        if (tid < 64) {
            const int bb = tid >> 1, half = tid & 1;
            const u16* hp = &hpk[bb*8 + half*4];
            u64 pk = (u64)hp[0] | ((u64)hp[1]<<16) | ((u64)hp[2]<<32) | ((u64)hp[3]<<48);
            const int ntb = bb >> 4, llb = ((ch&3)<<4) | (bb&15);
            astore(hnq + ((ch>>2)*2 + ntb)*128 + llb*2 + half, pk);
        }
        __syncthreads();                       // drain h stores
        if (tid == 0) afstore(myflags + ch*16, s+1);

        // logits off the critical path: issued after flag, drained at next step's syncs
        {
            float* lg = logits + (size_t)t*(NB*NU);
            for (int q = tid; q < NB*NU; q += 256) {
                int kk = q + (ch & 31)*NU;
                if (kk >= NB*NU) kk -= NB*NU;
                const int bb = kk / NU, uu = kk % NU;
                float sum = 0.f;
#pragma unroll
                for (int qq = 0; qq < 8; ++qq) sum += lwc[qq*NU + uu] * hblk[qq*NB + bb];
                atomicAdd(lg + kk, sum);
            }
        }
    }
}

__global__ __launch_bounds__(256) void logits_init(const float* __restrict__ lb, float* __restrict__ logits)
{
    int idx = blockIdx.x * 256 + threadIdx.x;
    if (idx < T_LEN*NB*NU) logits[idx] = lb[idx % NU];
}

// ---- softmax over 20 logits -> alphabet sin/cos mix; store (cosP, sinP) ----
__global__ __launch_bounds__(256)
void epilogue(const float* __restrict__ logits, const float* __restrict__ alphabet,
              float* __restrict__ cs)
{
    __shared__ float sa[NU*3], ca[NU*3];
    const int tid = threadIdx.x;
    if (tid < NU*3) { float al = alphabet[tid]; sa[tid] = sinf(al); ca[tid] = cosf(al); }
    __syncthreads();
    const int row = blockIdx.x*256 + tid;   // t*NB + b
    if (row >= T_LEN*NB) return;
    float lg[NU];
    float m = -1e30f;
#pragma unroll 4
    for (int u = 0; u < NU; ++u) { lg[u] = logits[(size_t)row*NU + u]; m = fmaxf(m, lg[u]); }
    float ssum = 0.f;
#pragma unroll 4
    for (int u = 0; u < NU; ++u) { lg[u] = expf(lg[u] - m); ssum += lg[u]; }
    float inv = 1.f / ssum;
#pragma unroll
    for (int i = 0; i < 3; ++i) {
        float sv = 0.f, cv = 0.f;
#pragma unroll 4
        for (int u = 0; u < NU; ++u) {
            float sw = lg[u] * inv;
            sv += sw * sa[u*3 + i];
            cv += sw * ca[u*3 + i];
        }
        float rinv = rsqrtf(fmaxf(sv*sv + cv*cv, 1e-30f));
        *(float2*)(cs + ((size_t)row*3 + i)*2) = make_float2(cv*rinv, sv*rinv);
    }
}

// ---- sequential chain extension: one lane per molecule ----
__global__ __launch_bounds__(64)
void geometry(const float* __restrict__ cs, float* __restrict__ out)
{
    const int b = threadIdx.x;
    if (b >= NB) return;
    const float blen[3] = {1.329f, 1.459f, 1.525f};
    const float bang[3] = {2.034f, 2.119f, 1.937f};
    float sT[3], cT[3];
#pragma unroll
    for (int i = 0; i < 3; ++i) { sT[i] = sinf(bang[i]); cT[i] = cosf(bang[i]); }

    float Ax=0.f,Ay=0.f,Az=1.f, Bx=0.f,By=1.f,Bz=0.f, Cx=1.f,Cy=0.f,Cz=0.f;
    out[(0*NB + b)*3 + 0] = 0.f; out[(0*NB + b)*3 + 1] = 0.f; out[(0*NB + b)*3 + 2] = 1.f;
    out[(1*NB + b)*3 + 0] = 0.f; out[(1*NB + b)*3 + 1] = 1.f; out[(1*NB + b)*3 + 2] = 0.f;
    out[(2*NB + b)*3 + 0] = 1.f; out[(2*NB + b)*3 + 1] = 0.f; out[(2*NB + b)*3 + 2] = 0.f;

    for (int t = 1; t < T_LEN; ++t) {
        float2 pc[3];
#pragma unroll
        for (int i = 0; i < 3; ++i)
            pc[i] = *(const float2*)(cs + (((size_t)t*NB + b)*3 + i)*2);
#pragma unroll
        for (int i = 0; i < 3; ++i) {
            float R = blen[i];
            float d2x = -R*cT[i], d2y = R*pc[i].x*sT[i], d2z = R*pc[i].y*sT[i];
            float bcx = Cx-Bx, bcy = Cy-By, bcz = Cz-Bz;
            float inv = rsqrtf(bcx*bcx + bcy*bcy + bcz*bcz);
            bcx *= inv; bcy *= inv; bcz *= inv;
            float abx = Bx-Ax, aby = By-Ay, abz = Bz-Az;
            float nx = aby*bcz - abz*bcy;
            float ny = abz*bcx - abx*bcz;
            float nz = abx*bcy - aby*bcx;
            inv = rsqrtf(fmaxf(nx*nx + ny*ny + nz*nz, 1e-30f));
            nx *= inv; ny *= inv; nz *= inv;
            float mx = ny*bcz - nz*bcy;
            float my = nz*bcx - nx*bcz;
            float mz = nx*bcy - ny*bcx;
            float Dx = bcx*d2x + mx*d2y + nx*d2z + Cx;
            float Dy = bcy*d2x + my*d2y + ny*d2z + Cy;
            float Dz = bcz*d2x + mz*d2y + nz*d2z + Cz;
            Ax=Bx; Ay=By; Az=Bz; Bx=Cx; By=Cy; Bz=Cz; Cx=Dx; Cy=Dy; Cz=Dz;
            const int r = 3 + (t-1)*3 + i;
            out[((size_t)r*NB + b)*3 + 0] = Dx;
            out[((size_t)r*NB + b)*3 + 1] = Dy;
            out[((size_t)r*NB + b)*3 + 2] = Dz;
        }
    }
}

extern "C" void kernel_launch(void* const* d_in, const int* in_sizes, int n_in,
                              void* d_out, int out_size, void* d_ws, size_t ws_size,
                              hipStream_t stream)
{
    (void)in_sizes; (void)n_in; (void)out_size; (void)ws_size;
    const float* seq   = (const float*)d_in[0];
    const float* w_ih0 = (const float*)d_in[2];
    const float* w_hh0 = (const float*)d_in[3];
    const float* b0    = (const float*)d_in[4];
    const float* w_ih1 = (const float*)d_in[5];
    const float* w_hh1 = (const float*)d_in[6];
    const float* b1    = (const float*)d_in[7];
    const float* lin_w = (const float*)d_in[8];
    const float* lin_b = (const float*)d_in[9];
    const float* alpha = (const float*)d_in[10];

    // workspace (~54.5 MB)
    char* ws = (char*)d_ws;
    size_t off = 0;
    u16* h0f   = (u16*)(ws + off); off += 52428800ull;   // [t][kc50][nt2][lane][i] bf16
    u16* hB    = (u16*)(ws + off); off += 204800ull;     // 2 bufs x 2 dirs x 25600 bf16
    int* flagsL0 = (int*)(ws + off); off += 12800ull;    // [d][ch] x 64B
    int* flagsL1 = (int*)(ws + off); off += 12800ull;
    float* logits = (float*)(ws + off); off += 1310720ull;  // [t][b][u] fp32
    float* cs = (float*)(ws + off); off += 393216ull;

    hipMemsetAsync(hB, 0, 204800 + 12800 + 12800, stream);   // hB + both flag arrays
    logits_init<<<dim3(1280), dim3(256), 0, stream>>>(lin_b, logits);

    lstm0_persist<<<dim3(2*NCH), dim3(256), 0, stream>>>(seq, w_ih0, w_hh0, b0, h0f, hB, flagsL0);

    hipMemsetAsync(hB, 0, 204800, stream);   // re-zero h state for layer 1
    lstm1_persist<<<dim3(2*NCH), dim3(256), 0, stream>>>(w_ih1, w_hh1, b1, lin_w, h0f, hB,
                                                         flagsL1, logits);

    epilogue<<<dim3(64), dim3(256), 0, stream>>>(logits, alpha, cs);
    geometry<<<dim3(1), dim3(64), 0, stream>>>(cs, (float*)d_out);
}

// Round 7
// 9663.781 us; speedup vs baseline: 4.9365x; 1.1242x over previous
//
#include <hip/hip_runtime.h>
#include <math.h>

#define T_LEN 512
#define NB    32
#define EMB_  41
#define IN0_  42
#define HID_  800
#define G4_   3200
#define IN1_  1600
#define NU    20
#define NCH   100   // blocks per direction
#define NREP  8     // logit replica buffers (contention 100/NREP per address)

typedef unsigned short u16;
typedef unsigned int   u32;
typedef unsigned long long u64;
typedef __attribute__((ext_vector_type(8))) short short8;
typedef __attribute__((ext_vector_type(4))) float f32x4;

__device__ __forceinline__ float bf2f(u16 v) {
    union { u32 u; float f; } c; c.u = ((u32)v) << 16; return c.f;
}
__device__ __forceinline__ u16 f2bf(float f) {
    union { float f; u32 u; } c; c.f = f;
    u32 r = (c.u + 0x7fffu + ((c.u >> 16) & 1u)) >> 16;
    return (u16)r;
}
__device__ __forceinline__ short cvt_hl(float v, int hl) {
    u16 hi = f2bf(v);
    return hl ? (short)f2bf(v - bf2f(hi)) : (short)hi;
}
__device__ __forceinline__ f32x4 mfma16(short8 a, short8 b, f32x4 c) {
    return __builtin_amdgcn_mfma_f32_16x16x32_bf16(a, b, c, 0, 0, 0);
}
__device__ __forceinline__ u64 aload(const u64* p) {
    return __hip_atomic_load(p, __ATOMIC_RELAXED, __HIP_MEMORY_SCOPE_AGENT);
}
__device__ __forceinline__ void astore(u64* p, u64 v) {
    __hip_atomic_store(p, v, __ATOMIC_RELAXED, __HIP_MEMORY_SCOPE_AGENT);
}
__device__ __forceinline__ int afload(const int* p) {
    return __hip_atomic_load(p, __ATOMIC_RELAXED, __HIP_MEMORY_SCOPE_AGENT);
}
__device__ __forceinline__ void afstore(int* p, int v) {
    __hip_atomic_store(p, v, __ATOMIC_RELAXED, __HIP_MEMORY_SCOPE_AGENT);
}

// ---------------- Layer 0: persistent, 200 blocks x 256 threads ----------------
// Distributed flag barrier: block (d,ch) owns flags[(d*NCH+ch)*16]; consumer thread
// tid<NCH spins on producer tid's flag. h-exchange staged once per block into LDS.
// seq staging hoisted before the poll; h0f store issued after the flag.
__global__ __launch_bounds__(256, 1)
void lstm0_persist(const float* __restrict__ seq, const float* __restrict__ wih0,
                   const float* __restrict__ whh0, const float* __restrict__ bias,
                   u16* __restrict__ h0f, u16* __restrict__ hB, int* __restrict__ flags)
{
    __shared__ __align__(16) float part[2048];          // 8 KB
    __shared__ __align__(16) u16 stageB[25600];         // 51.2 KB h-slab stage
    __shared__ __align__(16) float w0l[32*48];          // 6 KB
    __shared__ __align__(16) float xsl[32*48];          // 6 KB
    __shared__ u16 hpk[NB*8];
    const int tid = threadIdx.x;
    const int d = blockIdx.x / NCH, ch = blockIdx.x % NCH;
    const int w = tid >> 6, l = tid & 63;
    const int p = w & 1, hl = w >> 1;
    int* myflags = flags + d*NCH*16;

    short8 wreg[25];   // whh0 hi/lo A-frags, register-resident
    {
        const int m = l & 15, g = p*2 + (m>>3), j = ch*8 + (m&7);
        const float* base = whh0 + ((size_t)(d*G4_ + g*HID_ + j))*HID_ + (l>>4)*8;
#pragma unroll
        for (int kc = 0; kc < 25; ++kc) {
            float4 f0 = *(const float4*)(base + kc*32);
            float4 f1 = *(const float4*)(base + kc*32 + 4);
            short8 v;
            v[0]=cvt_hl(f0.x,hl); v[1]=cvt_hl(f0.y,hl); v[2]=cvt_hl(f0.z,hl); v[3]=cvt_hl(f0.w,hl);
            v[4]=cvt_hl(f1.x,hl); v[5]=cvt_hl(f1.y,hl); v[6]=cvt_hl(f1.z,hl); v[7]=cvt_hl(f1.w,hl);
            wreg[kc] = v;
        }
    }
    for (int idx = tid; idx < 32*EMB_; idx += 256) {
        int r = idx / EMB_, k = idx % EMB_;
        int ju_ = r >> 2, g = r & 3;
        w0l[r*48 + k] = wih0[((size_t)(d*G4_ + g*HID_ + ch*8 + ju_))*IN0_ + k];
    }
    const int ju = tid >> 5, b = tid & 31;
    const int j = ch*8 + ju;
    const int nt = b >> 4, n = b & 15;
    float biasr[4], wpos[4];
#pragma unroll
    for (int g = 0; g < 4; ++g) {
        biasr[g] = bias[d*G4_ + g*HID_ + j];
        wpos[g]  = wih0[((size_t)(d*G4_ + g*HID_ + j))*IN0_ + EMB_];
    }
    float creg = 0.f;
    __syncthreads();

    for (int s = 0; s < T_LEN; ++s) {
        const int t = d ? (T_LEN-1-s) : s;
        const u64* hq64 = (const u64*)(hB + (size_t)((s&1)*2 + d)*25600);
        u64*      hnq  = (u64*)(hB + (size_t)(((s&1)^1)*2 + d)*25600);

        // h-independent work BEFORE the poll (overlaps peers' flag propagation)
        for (int idx = tid; idx < 32*EMB_; idx += 256)
            xsl[(idx/EMB_)*48 + idx%EMB_] = seq[(size_t)t*(NB*EMB_) + idx];

        if (s > 0 && tid < NCH)
            while (afload(myflags + tid*16) < s) __builtin_amdgcn_s_sleep(1);
        __syncthreads();

        {   // stage the 51.2 KB B-slab once per block
            u64 tmp[25];
#pragma unroll
            for (int q = 0; q < 25; ++q) tmp[q] = aload(hq64 + tid + q*256);
#pragma unroll
            for (int q = 0; q < 25; ++q) ((u64*)stageB)[tid + q*256] = tmp[q];
        }
        __syncthreads();

        f32x4 acc0 = {0.f,0.f,0.f,0.f}, acc1 = {0.f,0.f,0.f,0.f};
#pragma unroll 5
        for (int kc = 0; kc < 25; ++kc) {
            short8 b0 = *(const short8*)(stageB + kc*1024 + l*8);
            short8 b1 = *(const short8*)(stageB + kc*1024 + 512 + l*8);
            acc0 = mfma16(wreg[kc], b0, acc0);
            acc1 = mfma16(wreg[kc], b1, acc1);
        }
        {
            const int mrow = (l>>4)*4, nn = l & 15;
#pragma unroll
            for (int r = 0; r < 4; ++r) {
                part[(((p*2+hl)*2 + 0)*16 + mrow + r)*16 + nn] = acc0[r];
                part[(((p*2+hl)*2 + 1)*16 + mrow + r)*16 + nn] = acc1[r];
            }
        }
        __syncthreads();

        float dot0 = 0.f, dot1 = 0.f, dot2 = 0.f, dot3 = 0.f;
        {
            const float* wr = &w0l[ju*4*48];
            const float* xr = &xsl[b*48];
#pragma unroll
            for (int k4 = 0; k4 < 40; k4 += 4) {
                float4 xk = *(const float4*)(xr + k4);
                float4 w0 = *(const float4*)(wr + 0*48 + k4);
                float4 w1 = *(const float4*)(wr + 1*48 + k4);
                float4 w2 = *(const float4*)(wr + 2*48 + k4);
                float4 w3 = *(const float4*)(wr + 3*48 + k4);
                dot0 += w0.x*xk.x + w0.y*xk.y + w0.z*xk.z + w0.w*xk.w;
                dot1 += w1.x*xk.x + w1.y*xk.y + w1.z*xk.z + w1.w*xk.w;
                dot2 += w2.x*xk.x + w2.y*xk.y + w2.z*xk.z + w2.w*xk.w;
                dot3 += w3.x*xk.x + w3.y*xk.y + w3.z*xk.z + w3.w*xk.w;
            }
            float xk = xr[40];
            dot0 += wr[0*48+40]*xk; dot1 += wr[1*48+40]*xk;
            dot2 += wr[2*48+40]*xk; dot3 += wr[3*48+40]*xk;
        }
        float v[4] = {dot0, dot1, dot2, dot3};
#pragma unroll
        for (int g = 0; g < 4; ++g) {
            const int pp = g >> 1, m = (g & 1)*8 + ju;
            v[g] += part[(((pp*2+0)*2 + nt)*16 + m)*16 + n]
                  + part[(((pp*2+1)*2 + nt)*16 + m)*16 + n]
                  + biasr[g] + (float)t * wpos[g];
        }
        float ig = 1.f/(1.f + expf(-v[0]));
        float fg = 1.f/(1.f + expf(-v[1]));
        float gg = tanhf(v[2]);
        float og = 1.f/(1.f + expf(-v[3]));
        creg = fg * creg + ig * gg;
        hpk[b*8 + ju] = f2bf(og * tanhf(creg));
        __syncthreads();

        u64 pk = 0; int xoff = 0;
        if (tid < 64) {
            const int bb = tid >> 1, half = tid & 1;
            const u16* hp = &hpk[bb*8 + half*4];
            pk = (u64)hp[0] | ((u64)hp[1]<<16) | ((u64)hp[2]<<32) | ((u64)hp[3]<<48);
            const int ntb = bb >> 4, llb = ((ch&3)<<4) | (bb&15);
            astore(hnq + ((ch>>2)*2 + ntb)*128 + llb*2 + half, pk);    // next-step h
            xoff = ((d*25 + (ch>>2))*2 + ntb)*128 + llb*2 + half;
        }
        __syncthreads();                       // drains vmcnt: hB stores at coherence point
        if (tid == 0) afstore(myflags + ch*16, s+1);
        if (tid < 64)                          // cross-dispatch store AFTER the flag
            ((u64*)(h0f + (size_t)t*51200))[xoff] = pk;
    }
}

// ---------------- Layer 1: persistent; fused x-GEMM + final linear ----------------
// x-MFMAs hoisted before the poll; logits into NREP replica buffers post-flag.
__global__ __launch_bounds__(256, 1)
void lstm1_persist(const float* __restrict__ wih1, const float* __restrict__ whh1,
                   const float* __restrict__ bias, const float* __restrict__ lin_w,
                   const u16* __restrict__ h0f, u16* __restrict__ hB,
                   int* __restrict__ flags, float* __restrict__ logits)
{
    __shared__ __align__(16) u16 wihL[2*50*512];        // 100 KB w_ih1 A-frags
    __shared__ __align__(16) u16 stageB[25600];         // 51.2 KB; part aliases first 8 KB
    __shared__ float lwc[8*NU];
    __shared__ float hblk[8*NB];
    __shared__ u16 hpk[NB*8];
    float* part = (float*)stageB;                       // 2048 floats, reused after MFMA
    const int tid = threadIdx.x;
    const int d = blockIdx.x / NCH, ch = blockIdx.x % NCH;
    const int w = tid >> 6, l = tid & 63;
    const int p = w & 1, hl = w >> 1;
    int* myflags = flags + d*NCH*16;

    short8 wreg[25];
    {
        const int m = l & 15, g = p*2 + (m>>3), j = ch*8 + (m&7);
        const float* base = whh1 + ((size_t)(d*G4_ + g*HID_ + j))*HID_ + (l>>4)*8;
#pragma unroll
        for (int kc = 0; kc < 25; ++kc) {
            float4 f0 = *(const float4*)(base + kc*32);
            float4 f1 = *(const float4*)(base + kc*32 + 4);
            short8 v;
            v[0]=cvt_hl(f0.x,hl); v[1]=cvt_hl(f0.y,hl); v[2]=cvt_hl(f0.z,hl); v[3]=cvt_hl(f0.w,hl);
            v[4]=cvt_hl(f1.x,hl); v[5]=cvt_hl(f1.y,hl); v[6]=cvt_hl(f1.z,hl); v[7]=cvt_hl(f1.w,hl);
            wreg[kc] = v;
        }
    }
    for (int o = tid; o < 6400; o += 256) {
        int pp = o / 3200, r = o % 3200, kc = r >> 6, ll = r & 63;
        int m = ll & 15, g = pp*2 + (m>>3), jj = ch*8 + (m&7);
        const float* base = wih1 + ((size_t)(d*G4_ + g*HID_ + jj))*IN1_ + kc*32 + (ll>>4)*8;
        float4 f0 = *(const float4*)base;
        float4 f1 = *(const float4*)(base + 4);
        short8 v;
        v[0]=(short)f2bf(f0.x); v[1]=(short)f2bf(f0.y); v[2]=(short)f2bf(f0.z); v[3]=(short)f2bf(f0.w);
        v[4]=(short)f2bf(f1.x); v[5]=(short)f2bf(f1.y); v[6]=(short)f2bf(f1.z); v[7]=(short)f2bf(f1.w);
        *(short8*)&wihL[o*8] = v;
    }
    if (tid < 8*NU) {
        int jju = tid / NU, u = tid % NU;
        lwc[tid] = lin_w[(size_t)u*IN1_ + d*HID_ + ch*8 + jju];
    }
    const int ju = tid >> 5, b = tid & 31;
    const int j = ch*8 + ju;
    const int nt = b >> 4, n = b & 15;
    float biasr[4];
#pragma unroll
    for (int g = 0; g < 4; ++g) biasr[g] = bias[d*G4_ + g*HID_ + j];
    float creg = 0.f;
    float* lrep = logits + (size_t)(ch & (NREP-1)) * (T_LEN*NB*NU);
    __syncthreads();

    for (int s = 0; s < T_LEN; ++s) {
        const int t = d ? (T_LEN-1-s) : s;
        const u64* hq64 = (const u64*)(hB + (size_t)((s&1)*2 + d)*25600);
        u64*      hnq  = (u64*)(hB + (size_t)(((s&1)^1)*2 + d)*25600);

        // x-part GEMM BEFORE the poll: depends only on h0f (previous dispatch)
        f32x4 acc0 = {0.f,0.f,0.f,0.f}, acc1 = {0.f,0.f,0.f,0.f};
        {
            const u16* xb = h0f + (size_t)t*51200;
#pragma unroll 5
            for (int kc = 0; kc < 25; ++kc) {
                const int idx = hl*25 + kc;
                short8 a  = *(const short8*)&wihL[(p*50 + idx)*512 + l*8];
                short8 b0 = *(const short8*)(xb + idx*1024 + l*8);
                short8 b1 = *(const short8*)(xb + idx*1024 + 512 + l*8);
                acc0 = mfma16(a, b0, acc0);
                acc1 = mfma16(a, b1, acc1);
            }
        }

        if (s > 0 && tid < NCH)
            while (afload(myflags + tid*16) < s) __builtin_amdgcn_s_sleep(1);
        __syncthreads();

        {
            u64 tmp[25];
#pragma unroll
            for (int q = 0; q < 25; ++q) tmp[q] = aload(hq64 + tid + q*256);
#pragma unroll
            for (int q = 0; q < 25; ++q) ((u64*)stageB)[tid + q*256] = tmp[q];
        }
        __syncthreads();

#pragma unroll 5
        for (int kc = 0; kc < 25; ++kc) {
            short8 b0 = *(const short8*)(stageB + kc*1024 + l*8);
            short8 b1 = *(const short8*)(stageB + kc*1024 + 512 + l*8);
            acc0 = mfma16(wreg[kc], b0, acc0);
            acc1 = mfma16(wreg[kc], b1, acc1);
        }
        __syncthreads();                      // all stageB reads done; part may alias
        {
            const int mrow = (l>>4)*4, nn = l & 15;
#pragma unroll
            for (int r = 0; r < 4; ++r) {
                part[(((p*2+hl)*2 + 0)*16 + mrow + r)*16 + nn] = acc0[r];
                part[(((p*2+hl)*2 + 1)*16 + mrow + r)*16 + nn] = acc1[r];
            }
        }
        __syncthreads();

        float v[4];
#pragma unroll
        for (int g = 0; g < 4; ++g) {
            const int pp = g >> 1, m = (g & 1)*8 + ju;
            v[g] = part[(((pp*2+0)*2 + nt)*16 + m)*16 + n]
                 + part[(((pp*2+1)*2 + nt)*16 + m)*16 + n] + biasr[g];
        }
        float ig = 1.f/(1.f + expf(-v[0]));
        float fg = 1.f/(1.f + expf(-v[1]));
        float gg = tanhf(v[2]);
        float og = 1.f/(1.f + expf(-v[3]));
        creg = fg * creg + ig * gg;
        float hn = og * tanhf(creg);
        hblk[ju*NB + b] = hn;
        hpk[b*8 + ju] = f2bf(hn);
        __syncthreads();

        if (tid < 64) {
            const int bb = tid >> 1, half = tid & 1;
            const u16* hp = &hpk[bb*8 + half*4];
            u64 pk = (u64)hp[0] | ((u64)hp[1]<<16) | ((u64)hp[2]<<32) | ((u64)hp[3]<<48);
            const int ntb = bb >> 4, llb = ((ch&3)<<4) | (bb&15);
            astore(hnq + ((ch>>2)*2 + ntb)*128 + llb*2 + half, pk);
        }
        __syncthreads();                       // drain h stores
        if (tid == 0) afstore(myflags + ch*16, s+1);

        // logits AFTER the flag: replica buffers cut per-address contention 8x;
        // completion drains during the next step's poll window
        {
            float* lg = lrep + (size_t)t*(NB*NU);
            for (int q = tid; q < NB*NU; q += 256) {
                int kk = q + (ch & 31)*NU;
                if (kk >= NB*NU) kk -= NB*NU;
                const int bb = kk / NU, uu = kk % NU;
                float sum = 0.f;
#pragma unroll
                for (int qq = 0; qq < 8; ++qq) sum += lwc[qq*NU + uu] * hblk[qq*NB + bb];
                atomicAdd(lg + kk, sum);
            }
        }
    }
}

// ---- sum replicas + lin_b -> softmax -> alphabet sin/cos mix; store (cosP, sinP) ----
__global__ __launch_bounds__(256)
void epilogue(const float* __restrict__ logits, const float* __restrict__ lin_b,
              const float* __restrict__ alphabet, float* __restrict__ cs)
{
    __shared__ float sa[NU*3], ca[NU*3], lb[NU];
    const int tid = threadIdx.x;
    if (tid < NU*3) { float al = alphabet[tid]; sa[tid] = sinf(al); ca[tid] = cosf(al); }
    if (tid < NU) lb[tid] = lin_b[tid];
    __syncthreads();
    const int row = blockIdx.x*256 + tid;   // t*NB + b
    if (row >= T_LEN*NB) return;
    float lg[NU];
#pragma unroll 4
    for (int u = 0; u < NU; ++u) lg[u] = lb[u];
    for (int r = 0; r < NREP; ++r) {
        const float* lp = logits + (size_t)r*(T_LEN*NB*NU) + (size_t)row*NU;
#pragma unroll 4
        for (int u = 0; u < NU; ++u) lg[u] += lp[u];
    }
    float m = -1e30f;
#pragma unroll 4
    for (int u = 0; u < NU; ++u) m = fmaxf(m, lg[u]);
    float ssum = 0.f;
#pragma unroll 4
    for (int u = 0; u < NU; ++u) { lg[u] = expf(lg[u] - m); ssum += lg[u]; }
    float inv = 1.f / ssum;
#pragma unroll
    for (int i = 0; i < 3; ++i) {
        float sv = 0.f, cv = 0.f;
#pragma unroll 4
        for (int u = 0; u < NU; ++u) {
            float sw = lg[u] * inv;
            sv += sw * sa[u*3 + i];
            cv += sw * ca[u*3 + i];
        }
        float rinv = rsqrtf(fmaxf(sv*sv + cv*cv, 1e-30f));
        *(float2*)(cs + ((size_t)row*3 + i)*2) = make_float2(cv*rinv, sv*rinv);
    }
}

// ---- sequential chain extension: one lane per molecule ----
__global__ __launch_bounds__(64)
void geometry(const float* __restrict__ cs, float* __restrict__ out)
{
    const int b = threadIdx.x;
    if (b >= NB) return;
    const float blen[3] = {1.329f, 1.459f, 1.525f};
    const float bang[3] = {2.034f, 2.119f, 1.937f};
    float sT[3], cT[3];
#pragma unroll
    for (int i = 0; i < 3; ++i) { sT[i] = sinf(bang[i]); cT[i] = cosf(bang[i]); }

    float Ax=0.f,Ay=0.f,Az=1.f, Bx=0.f,By=1.f,Bz=0.f, Cx=1.f,Cy=0.f,Cz=0.f;
    out[(0*NB + b)*3 + 0] = 0.f; out[(0*NB + b)*3 + 1] = 0.f; out[(0*NB + b)*3 + 2] = 1.f;
    out[(1*NB + b)*3 + 0] = 0.f; out[(1*NB + b)*3 + 1] = 1.f; out[(1*NB + b)*3 + 2] = 0.f;
    out[(2*NB + b)*3 + 0] = 1.f; out[(2*NB + b)*3 + 1] = 0.f; out[(2*NB + b)*3 + 2] = 0.f;

    for (int t = 1; t < T_LEN; ++t) {
        float2 pc[3];
#pragma unroll
        for (int i = 0; i < 3; ++i)
            pc[i] = *(const float2*)(cs + (((size_t)t*NB + b)*3 + i)*2);
#pragma unroll
        for (int i = 0; i < 3; ++i) {
            float R = blen[i];
            float d2x = -R*cT[i], d2y = R*pc[i].x*sT[i], d2z = R*pc[i].y*sT[i];
            float bcx = Cx-Bx, bcy = Cy-By, bcz = Cz-Bz;
            float inv = rsqrtf(bcx*bcx + bcy*bcy + bcz*bcz);
            bcx *= inv; bcy *= inv; bcz *= inv;
            float abx = Bx-Ax, aby = By-Ay, abz = Bz-Az;
            float nx = aby*bcz - abz*bcy;
            float ny = abz*bcx - abx*bcz;
            float nz = abx*bcy - aby*bcx;
            inv = rsqrtf(fmaxf(nx*nx + ny*ny + nz*nz, 1e-30f));
            nx *= inv; ny *= inv; nz *= inv;
            float mx = ny*bcz - nz*bcy;
            float my = nz*bcx - nx*bcz;
            float mz = nx*bcy - ny*bcx;
            float Dx = bcx*d2x + mx*d2y + nx*d2z + Cx;
            float Dy = bcy*d2x + my*d2y + ny*d2z + Cy;
            float Dz = bcz*d2x + mz*d2y + nz*d2z + Cz;
            Ax=Bx; Ay=By; Az=Bz; Bx=Cx; By=Cy; Bz=Cz; Cx=Dx; Cy=Dy; Cz=Dz;
            const int r = 3 + (t-1)*3 + i;
            out[((size_t)r*NB + b)*3 + 0] = Dx;
            out[((size_t)r*NB + b)*3 + 1] = Dy;
            out[((size_t)r*NB + b)*3 + 2] = Dz;
        }
    }
}

extern "C" void kernel_launch(void* const* d_in, const int* in_sizes, int n_in,
                              void* d_out, int out_size, void* d_ws, size_t ws_size,
                              hipStream_t stream)
{
    (void)in_sizes; (void)n_in; (void)out_size; (void)ws_size;
    const float* seq   = (const float*)d_in[0];
    const float* w_ih0 = (const float*)d_in[2];
    const float* w_hh0 = (const float*)d_in[3];
    const float* b0    = (const float*)d_in[4];
    const float* w_ih1 = (const float*)d_in[5];
    const float* w_hh1 = (const float*)d_in[6];
    const float* b1    = (const float*)d_in[7];
    const float* lin_w = (const float*)d_in[8];
    const float* lin_b = (const float*)d_in[9];
    const float* alpha = (const float*)d_in[10];

    // workspace (~63.5 MB)
    char* ws = (char*)d_ws;
    size_t off = 0;
    u16* h0f   = (u16*)(ws + off); off += 52428800ull;   // [t][kc50][nt2][lane][i] bf16
    u16* hB    = (u16*)(ws + off); off += 204800ull;     // 2 bufs x 2 dirs x 25600 bf16
    int* flagsL0 = (int*)(ws + off); off += 12800ull;    // [d][ch] x 64B
    int* flagsL1 = (int*)(ws + off); off += 12800ull;
    float* logits = (float*)(ws + off); off += (size_t)NREP*1310720ull;  // 8 replicas
    float* cs = (float*)(ws + off); off += 393216ull;

    hipMemsetAsync(hB, 0, 204800 + 12800 + 12800, stream);          // hB + both flag arrays
    hipMemsetAsync(logits, 0, (size_t)NREP*1310720ull, stream);     // replicas start at 0

    lstm0_persist<<<dim3(2*NCH), dim3(256), 0, stream>>>(seq, w_ih0, w_hh0, b0, h0f, hB, flagsL0);

    hipMemsetAsync(hB, 0, 204800, stream);   // re-zero h state for layer 1
    lstm1_persist<<<dim3(2*NCH), dim3(256), 0, stream>>>(w_ih1, w_hh1, b1, lin_w, h0f, hB,
                                                         flagsL1, logits);

    epilogue<<<dim3(64), dim3(256), 0, stream>>>(logits, lin_b, alpha, cs);
    geometry<<<dim3(1), dim3(64), 0, stream>>>(cs, (float*)d_out);
}